// Round 5
// baseline (2930.554 us; speedup 1.0000x reference)
//
#include <hip/hip_runtime.h>

// SimpleRNN: h_{t+1} = tanh(h Wh^T + x_t Wx^T + b), return h_1024.
// SEQ=1024, NB=64, HID=512, IN=512. W is [512][1024] = [Wh | Wx]. All fp32 I/O.
//
// Phase 1 (prepass): U[t][b][j] = x_t[b]·Wx[j] + b[j] as MFMA f16 GEMM, U f16 in ws.
// Phase 2 (recurrent): 256 WGs = 16 batch-quads x 16 row-slices (32 rows).
//   R3/R4 evidence: per-step cost is dominated by the cross-WG publish->IC->poll
//   round trip (~0.65us), not LDS traffic (R4 halved LDS, regressed). So: each
//   WG serves 4 batches in TWO STAGGERED joint phases — while pair0's publish
//   propagates through IC, the WG computes pair1 (latency hiding).
//   Sync words are u32 {tag16, h-f16} per row; 8-lane shuffle reduce kills the
//   LDS partial array and leaves ONE barrier per phase.

#define SEQ 1024
#define NB  64
#define HID 512

typedef _Float16 half2v __attribute__((ext_vector_type(2)));
typedef _Float16 f16x8  __attribute__((ext_vector_type(8)));
typedef float    f32x4  __attribute__((ext_vector_type(4)));

#if __has_builtin(__builtin_amdgcn_fdot2)
#define DOT2(a, b, c) __builtin_amdgcn_fdot2((a), (b), (c), false)
#else
static __device__ __forceinline__ float DOT2(half2v a, half2v b, float c) {
  return c + (float)a.x * (float)b.x + (float)a.y * (float)b.y;
}
#endif

static __device__ __forceinline__ float fast_tanh(float x) {
  // |pre-activation| <~ 16 here, so exp(2x) cannot overflow (proven R3/R4)
  float e = __expf(2.0f * x);
  return (e - 1.0f) / (e + 1.0f);
}

// ---------------------------------------------------------------- prepass ---
__global__ __launch_bounds__(256, 2)
void rnn_prepass(const float* __restrict__ X, const float* __restrict__ W,
                 const float* __restrict__ bias, _Float16* __restrict__ U) {
  __shared__ __align__(16) _Float16 As[128][40];
  __shared__ __align__(16) _Float16 Bs[128][40];
  const int tid = threadIdx.x;
  const int m0 = blockIdx.x * 128;
  const int n0 = blockIdx.y * 128;
  const int wave = tid >> 6, lane = tid & 63;
  const int wm = (wave >> 1) * 64, wn = (wave & 1) * 64;
  const int l15 = lane & 15, q = lane >> 4;

  f32x4 acc[4][4];
#pragma unroll
  for (int i = 0; i < 4; ++i)
#pragma unroll
    for (int j = 0; j < 4; ++j) acc[i][j] = (f32x4){0.f, 0.f, 0.f, 0.f};

  const int srow = tid >> 1;
  const int shalf = (tid & 1) * 16;

  for (int k0 = 0; k0 < 512; k0 += 32) {
    const float* asrc = X + (size_t)(m0 + srow) * 512 + k0 + shalf;
    const float* bsrc = W + (size_t)(n0 + srow) * 1024 + 512 + k0 + shalf;
    float4 a0 = *(const float4*)(asrc);
    float4 a1 = *(const float4*)(asrc + 4);
    float4 a2 = *(const float4*)(asrc + 8);
    float4 a3 = *(const float4*)(asrc + 12);
    float4 b0 = *(const float4*)(bsrc);
    float4 b1 = *(const float4*)(bsrc + 4);
    float4 b2 = *(const float4*)(bsrc + 8);
    float4 b3 = *(const float4*)(bsrc + 12);
    __syncthreads();
    f16x8 pa0 = {(_Float16)a0.x, (_Float16)a0.y, (_Float16)a0.z, (_Float16)a0.w,
                 (_Float16)a1.x, (_Float16)a1.y, (_Float16)a1.z, (_Float16)a1.w};
    f16x8 pa1 = {(_Float16)a2.x, (_Float16)a2.y, (_Float16)a2.z, (_Float16)a2.w,
                 (_Float16)a3.x, (_Float16)a3.y, (_Float16)a3.z, (_Float16)a3.w};
    f16x8 pb0 = {(_Float16)b0.x, (_Float16)b0.y, (_Float16)b0.z, (_Float16)b0.w,
                 (_Float16)b1.x, (_Float16)b1.y, (_Float16)b1.z, (_Float16)b1.w};
    f16x8 pb1 = {(_Float16)b2.x, (_Float16)b2.y, (_Float16)b2.z, (_Float16)b2.w,
                 (_Float16)b3.x, (_Float16)b3.y, (_Float16)b3.z, (_Float16)b3.w};
    *(f16x8*)&As[srow][shalf] = pa0;
    *(f16x8*)&As[srow][shalf + 8] = pa1;
    *(f16x8*)&Bs[srow][shalf] = pb0;
    *(f16x8*)&Bs[srow][shalf + 8] = pb1;
    __syncthreads();
    f16x8 av[4], bv[4];
#pragma unroll
    for (int i = 0; i < 4; ++i)
      av[i] = *(const f16x8*)&As[wm + i * 16 + l15][q * 8];
#pragma unroll
    for (int j = 0; j < 4; ++j)
      bv[j] = *(const f16x8*)&Bs[wn + j * 16 + l15][q * 8];
#pragma unroll
    for (int i = 0; i < 4; ++i)
#pragma unroll
      for (int j = 0; j < 4; ++j)
        acc[i][j] = __builtin_amdgcn_mfma_f32_16x16x32_f16(av[i], bv[j], acc[i][j], 0, 0, 0);
  }
  float bj[4];
#pragma unroll
  for (int j = 0; j < 4; ++j) bj[j] = bias[n0 + wn + j * 16 + l15];
#pragma unroll
  for (int i = 0; i < 4; ++i)
#pragma unroll
    for (int j = 0; j < 4; ++j)
#pragma unroll
      for (int r = 0; r < 4; ++r) {
        int m = m0 + wm + i * 16 + q * 4 + r;
        int n = n0 + wn + j * 16 + l15;
        U[(size_t)m * 512 + n] = (_Float16)(acc[i][j][r] + bj[j]);
      }
}

// -------------------------------------------------------------- recurrent ---
// hbuf layout: u32 [parity 2][batch 64][row 512], word = {tag16 (step), h f16}.
__global__ __launch_bounds__(256, 1)
void rnn_recur(const float* __restrict__ W, const _Float16* __restrict__ U,
               unsigned int* hbuf, float* __restrict__ out) {
  extern __shared__ char dynpad[];   // sized at launch to force >80KB -> 1 WG/CU
  (void)dynpad;
  const int blk = blockIdx.x;
  const int p = blk & 15;            // batch quad: batches 4p..4p+3
  const int g = blk >> 4;            // row-slice 0..15: rows 32g..32g+31
  const int tid = threadIdx.x;
  const int rl = tid >> 3;           // local row 0..31
  const int ks = tid & 7;            // k-chunk 0..7 (64 k each)
  const int row = 32 * g + rl;       // global hidden row this thread helps

  // Weights: thread-order chunks; each thread reads ONLY its own column ->
  // never needs a barrier. 8 chunks x 256 thr x 16B = 32 KB.
  __shared__ __align__(16) f16x8 wl[8][256];
  // Staged h for 4 chains, chunk-padded (stride 36 u32 -> conflict-free
  // 8-way-broadcast b128 reads, 16B-aligned). 4 x 1152 B.
  __shared__ __align__(16) unsigned int hst[4][8 * 36];

  // One-time weight load: row `row`, k in [64ks, 64ks+64)
  {
    const float* wrow = W + (size_t)row * 1024 + ks * 64;
#pragma unroll
    for (int i = 0; i < 8; ++i) {
      float4 wa = *(const float4*)(wrow + 8 * i);
      float4 wb = *(const float4*)(wrow + 8 * i + 4);
      f16x8 pk = {(_Float16)wa.x, (_Float16)wa.y, (_Float16)wa.z, (_Float16)wa.w,
                  (_Float16)wb.x, (_Float16)wb.y, (_Float16)wb.z, (_Float16)wb.w};
      wl[i][tid] = pk;
    }
  }

  float hout[4];
#pragma unroll
  for (int c = 0; c < 4; ++c) hout[c] = 0.f;

  for (int t = 0; t < SEQ; ++t) {
#pragma unroll
    for (int ph = 0; ph < 2; ++ph) {
      const int bA = 4 * p + 2 * ph;
      const int bB = bA + 1;

      // U prefetch for publisher lanes (issued before the poll)
      float uA = 0.f, uB = 0.f;
      if (ks == 0) {
        uA = (float)U[((size_t)t * NB + bA) * HID + row];
        uB = (float)U[((size_t)t * NB + bB) * HID + row];
      }

      // poll rows {2tid, 2tid+1} of both batches for tag t (parity t&1)
      {
        const unsigned long long* pA =
            (const unsigned long long*)(hbuf + ((size_t)(t & 1) * NB + bA) * HID) + tid;
        const unsigned long long* pB =
            (const unsigned long long*)(hbuf + ((size_t)(t & 1) * NB + bB) * HID) + tid;
        const unsigned int tg = (unsigned int)t & 0xFFFFu;
        unsigned long long eA = 0, eB = 0;
        bool dA = false, dB = false;
        int spins = 0;
        do {
          if (!dA) {
            eA = __hip_atomic_load(pA, __ATOMIC_RELAXED, __HIP_MEMORY_SCOPE_AGENT);
            dA = (((unsigned int)(eA >> 16) & 0xFFFFu) == tg) &&
                 ((unsigned int)(eA >> 48) == tg);
          }
          if (!dB) {
            eB = __hip_atomic_load(pB, __ATOMIC_RELAXED, __HIP_MEMORY_SCOPE_AGENT);
            dB = (((unsigned int)(eB >> 16) & 0xFFFFu) == tg) &&
                 ((unsigned int)(eB >> 48) == tg);
          }
          if (++spins > 3) __builtin_amdgcn_s_sleep(1);  // throttle IC storm
        } while (!(dA && dB));
        // pack the two f16 h values {row 2tid, row 2tid+1} into one u32
        unsigned int hA = ((unsigned int)eA & 0xFFFFu) |
                          ((unsigned int)(eA >> 16) & 0xFFFF0000u);
        unsigned int hB = ((unsigned int)eB & 0xFFFFu) |
                          ((unsigned int)(eB >> 16) & 0xFFFF0000u);
        hst[2 * ph + 0][(tid >> 5) * 36 + (tid & 31)] = hA;
        hst[2 * ph + 1][(tid >> 5) * 36 + (tid & 31)] = hB;
      }
      __syncthreads();  // the ONE barrier per phase: h staged before compute

      // joint dual-batch dot: 8 x (1 w-b128 + 2 h-b128(8-way bc) + 8 dot2)
      float sA = 0.f, sB = 0.f;
      {
        const unsigned int* hA32 = &hst[2 * ph + 0][ks * 36];
        const unsigned int* hB32 = &hst[2 * ph + 1][ks * 36];
#pragma unroll
        for (int i = 0; i < 8; ++i) {
          f16x8 wv = wl[i][tid];
          f16x8 av = *(const f16x8*)&hA32[i * 4];
          f16x8 bv = *(const f16x8*)&hB32[i * 4];
          half2v w0 = {wv[0], wv[1]}, w1 = {wv[2], wv[3]};
          half2v w2 = {wv[4], wv[5]}, w3 = {wv[6], wv[7]};
          half2v a0 = {av[0], av[1]}, a1 = {av[2], av[3]};
          half2v a2 = {av[4], av[5]}, a3 = {av[6], av[7]};
          half2v b0 = {bv[0], bv[1]}, b1 = {bv[2], bv[3]};
          half2v b2 = {bv[4], bv[5]}, b3 = {bv[6], bv[7]};
          sA = DOT2(w0, a0, sA); sA = DOT2(w1, a1, sA);
          sA = DOT2(w2, a2, sA); sA = DOT2(w3, a3, sA);
          sB = DOT2(w0, b0, sB); sB = DOT2(w1, b1, sB);
          sB = DOT2(w2, b2, sB); sB = DOT2(w3, b3, sB);
        }
      }
      // 8-lane k-reduce in-register (no LDS, no barrier)
#pragma unroll
      for (int m = 1; m < 8; m <<= 1) {
        sA += __shfl_xor(sA, m);
        sB += __shfl_xor(sB, m);
      }

      if (ks == 0) {
        float hAf = fast_tanh(sA + uA);
        float hBf = fast_tanh(sB + uB);
        hout[2 * ph + 0] = hAf;
        hout[2 * ph + 1] = hBf;
        unsigned int tagp = ((unsigned int)(t + 1) & 0xFFFFu) << 16;
        unsigned int wA = tagp |
            (unsigned int)__builtin_bit_cast(unsigned short, (_Float16)hAf);
        unsigned int wB = tagp |
            (unsigned int)__builtin_bit_cast(unsigned short, (_Float16)hBf);
        // publish row of h_{t+1}, parity (t+1)&1. Overwrite of h_{t-1} is
        // safe: observing tag==t on ALL rows implies every WG of this group
        // finished staging h_{t-1} (same induction as R3/R4).
        __hip_atomic_store(
            hbuf + ((size_t)((t + 1) & 1) * NB + bA) * HID + row, wA,
            __ATOMIC_RELAXED, __HIP_MEMORY_SCOPE_AGENT);
        __hip_atomic_store(
            hbuf + ((size_t)((t + 1) & 1) * NB + bB) * HID + row, wB,
            __ATOMIC_RELAXED, __HIP_MEMORY_SCOPE_AGENT);
      }
      // no second barrier: next write to hst[2ph..] is next step's SAME phase,
      // separated from this compute by the OTHER phase's barrier.
    }
  }
  if (ks == 0) {
#pragma unroll
    for (int c = 0; c < 4; ++c)
      out[(size_t)(4 * p + c) * HID + row] = hout[c];
  }
}

// ------------------------------------------------------------------- host ---
extern "C" void kernel_launch(void* const* d_in, const int* in_sizes, int n_in,
                              void* d_out, int out_size, void* d_ws, size_t ws_size,
                              hipStream_t stream) {
  const float* X    = (const float*)d_in[0];  // [1024][64][512]
  const float* W    = (const float*)d_in[1];  // [512][1024]
  const float* bias = (const float*)d_in[2];  // [512]
  float* out = (float*)d_out;                 // [64][512]

  // ws layout: U f16 (64 MiB) | hbuf u32[2][64][512] (256 KiB)
  char* ws = (char*)d_ws;
  _Float16* U = (_Float16*)ws;
  unsigned int* hbuf = (unsigned int*)(ws + (size_t)SEQ * NB * HID * 2);

  // parity-0 = h_0 = 0 with tag 0; parity-1 keeps 0xAA poison (tag 0xAAAA
  // can never match a step tag <= 1024)
  hipMemsetAsync(hbuf, 0, (size_t)NB * HID * 4, stream);

  rnn_prepass<<<dim3(512, 4), dim3(256), 0, stream>>>(X, W, bias, U);

  const float* Wp = W;
  const _Float16* Up = U;
  unsigned int* hb = hbuf;
  float* op = out;
  void* args[] = {(void*)&Wp, (void*)&Up, (void*)&hb, (void*)&op};
  // dynamic LDS pad: static ~37 KB + 50 KB > 80 KB -> guarantees 1 WG/CU
  const size_t dyn = 50 * 1024;
  hipError_t e = hipLaunchCooperativeKernel(
      reinterpret_cast<void*>(rnn_recur), dim3(256), dim3(256), args,
      (unsigned int)dyn, stream);
  if (e != hipSuccess) {
    rnn_recur<<<dim3(256), dim3(256), dyn, stream>>>(Wp, Up, hb, op);
  }
}

// Round 6
// 2176.159 us; speedup vs baseline: 1.3467x; 1.3467x over previous
//
#include <hip/hip_runtime.h>

// SimpleRNN: h_{t+1} = tanh(h Wh^T + x_t Wx^T + b), return h_1024.
// SEQ=1024, NB=64, HID=512, IN=512. W is [512][1024] = [Wh | Wx]. All fp32 I/O.
//
// Phase 1 (prepass): U[t][b][j] = x_t[b]·Wx[j] + b[j] as MFMA f16 GEMM, U f16 in ws.
// Phase 2 (recurrent): PROVEN R3 geometry — 256 WGs = 64 batches x 4 row-slices
//   (128 rows, 128 KB f16 weights in LDS; sync circle = 4 WGs, all same XCD).
//   R4 (circle 8) and R5 (circle 16, 2 phases) both regressed: step time grows
//   with circle size. R6 keeps circle 4 and removes R3's per-step overheads:
//   - k-chunk in lane-low-bits -> shuffle k-reduce (no part[] LDS, no SYNC2)
//   - ONE barrier/step; hlds parity double-buffer closes the reuse race
//   - weights self-written/self-read per thread (no weight barrier)
//   - poll backoff after 2 spins

#define SEQ 1024
#define NB  64
#define HID 512

typedef _Float16 half2v __attribute__((ext_vector_type(2)));
typedef _Float16 f16x8  __attribute__((ext_vector_type(8)));
typedef float    f32x4  __attribute__((ext_vector_type(4)));

#if __has_builtin(__builtin_amdgcn_fdot2)
#define DOT2(a, b, c) __builtin_amdgcn_fdot2((a), (b), (c), false)
#else
static __device__ __forceinline__ float DOT2(half2v a, half2v b, float c) {
  return c + (float)a.x * (float)b.x + (float)a.y * (float)b.y;
}
#endif

static __device__ __forceinline__ float fast_tanh(float x) {
  float e = __expf(2.0f * x);
  return (e - 1.0f) / (e + 1.0f);
}

// ---------------------------------------------------------------- prepass ---
__global__ __launch_bounds__(256, 2)
void rnn_prepass(const float* __restrict__ X, const float* __restrict__ W,
                 const float* __restrict__ bias, _Float16* __restrict__ U) {
  __shared__ __align__(16) _Float16 As[128][40];
  __shared__ __align__(16) _Float16 Bs[128][40];
  const int tid = threadIdx.x;
  const int m0 = blockIdx.x * 128;
  const int n0 = blockIdx.y * 128;
  const int wave = tid >> 6, lane = tid & 63;
  const int wm = (wave >> 1) * 64, wn = (wave & 1) * 64;
  const int l15 = lane & 15, q = lane >> 4;

  f32x4 acc[4][4];
#pragma unroll
  for (int i = 0; i < 4; ++i)
#pragma unroll
    for (int j = 0; j < 4; ++j) acc[i][j] = (f32x4){0.f, 0.f, 0.f, 0.f};

  const int srow = tid >> 1;
  const int shalf = (tid & 1) * 16;

  for (int k0 = 0; k0 < 512; k0 += 32) {
    const float* asrc = X + (size_t)(m0 + srow) * 512 + k0 + shalf;
    const float* bsrc = W + (size_t)(n0 + srow) * 1024 + 512 + k0 + shalf;
    float4 a0 = *(const float4*)(asrc);
    float4 a1 = *(const float4*)(asrc + 4);
    float4 a2 = *(const float4*)(asrc + 8);
    float4 a3 = *(const float4*)(asrc + 12);
    float4 b0 = *(const float4*)(bsrc);
    float4 b1 = *(const float4*)(bsrc + 4);
    float4 b2 = *(const float4*)(bsrc + 8);
    float4 b3 = *(const float4*)(bsrc + 12);
    __syncthreads();
    f16x8 pa0 = {(_Float16)a0.x, (_Float16)a0.y, (_Float16)a0.z, (_Float16)a0.w,
                 (_Float16)a1.x, (_Float16)a1.y, (_Float16)a1.z, (_Float16)a1.w};
    f16x8 pa1 = {(_Float16)a2.x, (_Float16)a2.y, (_Float16)a2.z, (_Float16)a2.w,
                 (_Float16)a3.x, (_Float16)a3.y, (_Float16)a3.z, (_Float16)a3.w};
    f16x8 pb0 = {(_Float16)b0.x, (_Float16)b0.y, (_Float16)b0.z, (_Float16)b0.w,
                 (_Float16)b1.x, (_Float16)b1.y, (_Float16)b1.z, (_Float16)b1.w};
    f16x8 pb1 = {(_Float16)b2.x, (_Float16)b2.y, (_Float16)b2.z, (_Float16)b2.w,
                 (_Float16)b3.x, (_Float16)b3.y, (_Float16)b3.z, (_Float16)b3.w};
    *(f16x8*)&As[srow][shalf] = pa0;
    *(f16x8*)&As[srow][shalf + 8] = pa1;
    *(f16x8*)&Bs[srow][shalf] = pb0;
    *(f16x8*)&Bs[srow][shalf + 8] = pb1;
    __syncthreads();
    f16x8 av[4], bv[4];
#pragma unroll
    for (int i = 0; i < 4; ++i)
      av[i] = *(const f16x8*)&As[wm + i * 16 + l15][q * 8];
#pragma unroll
    for (int j = 0; j < 4; ++j)
      bv[j] = *(const f16x8*)&Bs[wn + j * 16 + l15][q * 8];
#pragma unroll
    for (int i = 0; i < 4; ++i)
#pragma unroll
      for (int j = 0; j < 4; ++j)
        acc[i][j] = __builtin_amdgcn_mfma_f32_16x16x32_f16(av[i], bv[j], acc[i][j], 0, 0, 0);
  }
  float bj[4];
#pragma unroll
  for (int j = 0; j < 4; ++j) bj[j] = bias[n0 + wn + j * 16 + l15];
#pragma unroll
  for (int i = 0; i < 4; ++i)
#pragma unroll
    for (int j = 0; j < 4; ++j)
#pragma unroll
      for (int r = 0; r < 4; ++r) {
        int m = m0 + wm + i * 16 + q * 4 + r;
        int n = n0 + wn + j * 16 + l15;
        U[(size_t)m * 512 + n] = (_Float16)(acc[i][j][r] + bj[j]);
      }
}

// -------------------------------------------------------------- recurrent ---
// hbuf: u64 [parity 2][batch 64][word 256]; word j = {tag32, h f16 rows 2j,2j+1}
__global__ __launch_bounds__(256, 1)
void rnn_recur(const float* __restrict__ W, const _Float16* __restrict__ U,
               unsigned long long* hbuf, float* __restrict__ out) {
  const int blk = blockIdx.x;
  const int batch = blk & 63;  // circle {b, b+64, b+128, b+192}: same XCD (%8)
  const int g = blk >> 6;      // row-slice 0..3 (rows 128g..128g+127)
  const int tid = threadIdx.x;
  const int ks = tid & 7;      // k-chunk 0..7 (64 k each) — LANE-LOCAL for shfl
  const int rg = tid >> 3;     // row group 0..31 (4 rows: 128g + 4rg + i)

  // 128 KB weights (thread-order: self-write, self-read, never a barrier)
  __shared__ __align__(16) f16x8 wl[32][256];  // [i*8+q][tid]
  // h_t staged, parity double-buffered (closes reuse race without 2nd barrier)
  __shared__ __align__(16) half2v hlds[2][256];

  // One-time: rows 128g+4rg+i, cols [64ks, 64ks+64) -> f16 -> own chunks
#pragma unroll
  for (int i = 0; i < 4; ++i) {
    const float* wrow = W + (size_t)(128 * g + 4 * rg + i) * 1024 + ks * 64;
#pragma unroll
    for (int q = 0; q < 8; ++q) {
      float4 wa = *(const float4*)(wrow + 8 * q);
      float4 wb = *(const float4*)(wrow + 8 * q + 4);
      f16x8 pk = {(_Float16)wa.x, (_Float16)wa.y, (_Float16)wa.z, (_Float16)wa.w,
                  (_Float16)wb.x, (_Float16)wb.y, (_Float16)wb.z, (_Float16)wb.w};
      wl[i * 8 + q][tid] = pk;
    }
  }

  const unsigned long long* U64 = (const unsigned long long*)U;
  unsigned long long* hb = hbuf + (size_t)batch * 256;  // parity stride NB*256

  float hv0 = 0.f, hv1 = 0.f, hv2 = 0.f, hv3 = 0.f;  // publisher-held h rows
  for (int t = 0; t < SEQ; ++t) {
    // U prefetch: publishers need 4 halves (rows 128g+4rg..+3), one u64
    unsigned long long uld = 0;
    if (ks == 0)
      uld = U64[(((size_t)t * NB + batch) * HID + 128 * g + 4 * rg) >> 2];

    // poll word tid (rows 2tid,2tid+1) for tag t, parity t&1; stage to LDS
    {
      const unsigned long long* src = hb + (size_t)(t & 1) * (NB * 256) + tid;
      unsigned long long e;
      int spins = 0;
      for (;;) {
        e = __hip_atomic_load(src, __ATOMIC_RELAXED, __HIP_MEMORY_SCOPE_AGENT);
        if ((unsigned int)(e >> 32) == (unsigned int)t) break;
        if (++spins > 2) __builtin_amdgcn_s_sleep(1);
      }
      hlds[t & 1][tid] = __builtin_bit_cast(half2v, (unsigned int)e);
    }
    __syncthreads();  // the ONE barrier: h_t staged before compute

    // 4 rows x 64 k: 32 w-b128 (2 lanes/bank = free) + 8 h-b128 (8-way bc)
    float a0 = 0.f, a1 = 0.f, a2 = 0.f, a3 = 0.f;
    const half2v* hp = &hlds[t & 1][ks * 32];
#pragma unroll
    for (int q = 0; q < 8; ++q) {
      f16x8 h8 = *(const f16x8*)&hp[q * 4];
      half2v h0 = {h8[0], h8[1]}, h1 = {h8[2], h8[3]};
      half2v h2 = {h8[4], h8[5]}, h3 = {h8[6], h8[7]};
#pragma unroll
      for (int i = 0; i < 4; ++i) {
        f16x8 wv = wl[i * 8 + q][tid];
        half2v w0 = {wv[0], wv[1]}, w1 = {wv[2], wv[3]};
        half2v w2 = {wv[4], wv[5]}, w3 = {wv[6], wv[7]};
        float* ai = (i == 0) ? &a0 : (i == 1) ? &a1 : (i == 2) ? &a2 : &a3;
        *ai = DOT2(w0, h0, *ai); *ai = DOT2(w1, h1, *ai);
        *ai = DOT2(w2, h2, *ai); *ai = DOT2(w3, h3, *ai);
      }
    }
    // k-reduce across the 8 ks-lanes (contiguous lanes, wave-local)
#pragma unroll
    for (int m = 1; m < 8; m <<= 1) {
      a0 += __shfl_xor(a0, m);
      a1 += __shfl_xor(a1, m);
      a2 += __shfl_xor(a2, m);
      a3 += __shfl_xor(a3, m);
    }

    if (ks == 0) {
      f16x8 u8;
      *(unsigned long long*)&u8 = uld;  // 4 halves valid
      hv0 = fast_tanh(a0 + (float)u8[0]);
      hv1 = fast_tanh(a1 + (float)u8[1]);
      hv2 = fast_tanh(a2 + (float)u8[2]);
      hv3 = fast_tanh(a3 + (float)u8[3]);
      half2v p01; p01.x = (_Float16)hv0; p01.y = (_Float16)hv1;
      half2v p23; p23.x = (_Float16)hv2; p23.y = (_Float16)hv3;
      unsigned long long tg = (unsigned long long)(unsigned int)(t + 1) << 32;
      unsigned long long w01 = tg | __builtin_bit_cast(unsigned int, p01);
      unsigned long long w23 = tg | __builtin_bit_cast(unsigned int, p23);
      // publish words {64g+2rg, +1} of h_{t+1}, parity (t+1)&1.
      // h_{t-1} overwrite safe: tag==t observed on all words this step implies
      // every circle WG finished staging h_{t-1} (R3 induction).
      unsigned long long* dst =
          hb + (size_t)((t + 1) & 1) * (NB * 256) + 64 * g + 2 * rg;
      __hip_atomic_store(dst, w01, __ATOMIC_RELAXED, __HIP_MEMORY_SCOPE_AGENT);
      __hip_atomic_store(dst + 1, w23, __ATOMIC_RELAXED, __HIP_MEMORY_SCOPE_AGENT);
    }
    // no 2nd barrier: next step's hlds write goes to the OTHER parity buffer;
    // the (t+2) rewrite of this parity is fenced by barrier(t+1).
  }
  if (ks == 0) {
    float* o = out + (size_t)batch * HID + 128 * g + 4 * rg;
    o[0] = hv0; o[1] = hv1; o[2] = hv2; o[3] = hv3;
  }
}

// ------------------------------------------------------------------- host ---
extern "C" void kernel_launch(void* const* d_in, const int* in_sizes, int n_in,
                              void* d_out, int out_size, void* d_ws, size_t ws_size,
                              hipStream_t stream) {
  const float* X    = (const float*)d_in[0];  // [1024][64][512]
  const float* W    = (const float*)d_in[1];  // [512][1024]
  const float* bias = (const float*)d_in[2];  // [512]
  float* out = (float*)d_out;                 // [64][512]

  // ws layout: U f16 (64 MiB) | hbuf u64[2][64][256] (256 KiB)
  char* ws = (char*)d_ws;
  _Float16* U = (_Float16*)ws;
  unsigned long long* hbuf =
      (unsigned long long*)(ws + (size_t)SEQ * NB * HID * 2);

  // parity-0 = h_0 = 0 with tag 0; parity-1 keeps 0xAA poison (tag 0xAAAAAAAA
  // never matches a step tag <= 1024)
  hipMemsetAsync(hbuf, 0, (size_t)NB * 256 * 8, stream);

  rnn_prepass<<<dim3(512, 4), dim3(256), 0, stream>>>(X, W, bias, U);

  const float* Wp = W;
  const _Float16* Up = U;
  unsigned long long* hb = hbuf;
  float* op = out;
  void* args[] = {(void*)&Wp, (void*)&Up, (void*)&hb, (void*)&op};
  // cooperative launch: all 256 WGs co-resident (130 KB LDS -> 1 WG/CU anyway)
  hipError_t e = hipLaunchCooperativeKernel(
      reinterpret_cast<void*>(rnn_recur), dim3(256), dim3(256), args, 0, stream);
  if (e != hipSuccess) {
    rnn_recur<<<dim3(256), dim3(256), 0, stream>>>(Wp, Up, hb, op);
  }
}

// Round 7
// 1835.859 us; speedup vs baseline: 1.5963x; 1.1854x over previous
//
#include <hip/hip_runtime.h>

// SimpleRNN: h_{t+1} = tanh(h Wh^T + x_t Wx^T + b), return h_1024.
// SEQ=1024, NB=64, HID=512, IN=512. W is [512][1024] = [Wh | Wx]. All fp32 I/O.
//
// Phase 1 (prepass): U[t][b][j] = x_t[b]·Wx[j] + b[j] as MFMA f16 GEMM, U f16 in ws.
// Phase 2 (recurrent): circle-4 geometry (R3-proven optimum: 64 batches x 4
//   row-slices of 128 rows; R4/R5 showed bigger circles regress).
//   R6 post-mortem fixes baked in:
//   - h staged at stride-36 u32 (R5-proven zero-conflict; R6's stride-32 gave
//     8-way aliasing -> 1.0e8 SQ_LDS_BANK_CONFLICT)
//   - weight chunks 0..15 kept in VGPRs from init (64 regs), 16..23 prefetched
//     to regs BEFORE the h-poll (LDS latency hidden under spin), 24..31 streamed
//   - shuffle k-reduce (no part[], one barrier/step), tagged-u64 h publish

#define SEQ 1024
#define NB  64
#define HID 512

typedef _Float16 half2v __attribute__((ext_vector_type(2)));
typedef _Float16 f16x8  __attribute__((ext_vector_type(8)));
typedef float    f32x4  __attribute__((ext_vector_type(4)));

#if __has_builtin(__builtin_amdgcn_fdot2)
#define DOT2(a, b, c) __builtin_amdgcn_fdot2((a), (b), (c), false)
#else
static __device__ __forceinline__ float DOT2(half2v a, half2v b, float c) {
  return c + (float)a.x * (float)b.x + (float)a.y * (float)b.y;
}
#endif

static __device__ __forceinline__ float fast_tanh(float x) {
  float e = __expf(2.0f * x);
  return (e - 1.0f) / (e + 1.0f);
}

// ---------------------------------------------------------------- prepass ---
__global__ __launch_bounds__(256, 2)
void rnn_prepass(const float* __restrict__ X, const float* __restrict__ W,
                 const float* __restrict__ bias, _Float16* __restrict__ U) {
  __shared__ __align__(16) _Float16 As[128][40];
  __shared__ __align__(16) _Float16 Bs[128][40];
  const int tid = threadIdx.x;
  const int m0 = blockIdx.x * 128;
  const int n0 = blockIdx.y * 128;
  const int wave = tid >> 6, lane = tid & 63;
  const int wm = (wave >> 1) * 64, wn = (wave & 1) * 64;
  const int l15 = lane & 15, q = lane >> 4;

  f32x4 acc[4][4];
#pragma unroll
  for (int i = 0; i < 4; ++i)
#pragma unroll
    for (int j = 0; j < 4; ++j) acc[i][j] = (f32x4){0.f, 0.f, 0.f, 0.f};

  const int srow = tid >> 1;
  const int shalf = (tid & 1) * 16;

  for (int k0 = 0; k0 < 512; k0 += 32) {
    const float* asrc = X + (size_t)(m0 + srow) * 512 + k0 + shalf;
    const float* bsrc = W + (size_t)(n0 + srow) * 1024 + 512 + k0 + shalf;
    float4 a0 = *(const float4*)(asrc);
    float4 a1 = *(const float4*)(asrc + 4);
    float4 a2 = *(const float4*)(asrc + 8);
    float4 a3 = *(const float4*)(asrc + 12);
    float4 b0 = *(const float4*)(bsrc);
    float4 b1 = *(const float4*)(bsrc + 4);
    float4 b2 = *(const float4*)(bsrc + 8);
    float4 b3 = *(const float4*)(bsrc + 12);
    __syncthreads();
    f16x8 pa0 = {(_Float16)a0.x, (_Float16)a0.y, (_Float16)a0.z, (_Float16)a0.w,
                 (_Float16)a1.x, (_Float16)a1.y, (_Float16)a1.z, (_Float16)a1.w};
    f16x8 pa1 = {(_Float16)a2.x, (_Float16)a2.y, (_Float16)a2.z, (_Float16)a2.w,
                 (_Float16)a3.x, (_Float16)a3.y, (_Float16)a3.z, (_Float16)a3.w};
    f16x8 pb0 = {(_Float16)b0.x, (_Float16)b0.y, (_Float16)b0.z, (_Float16)b0.w,
                 (_Float16)b1.x, (_Float16)b1.y, (_Float16)b1.z, (_Float16)b1.w};
    f16x8 pb1 = {(_Float16)b2.x, (_Float16)b2.y, (_Float16)b2.z, (_Float16)b2.w,
                 (_Float16)b3.x, (_Float16)b3.y, (_Float16)b3.z, (_Float16)b3.w};
    *(f16x8*)&As[srow][shalf] = pa0;
    *(f16x8*)&As[srow][shalf + 8] = pa1;
    *(f16x8*)&Bs[srow][shalf] = pb0;
    *(f16x8*)&Bs[srow][shalf + 8] = pb1;
    __syncthreads();
    f16x8 av[4], bv[4];
#pragma unroll
    for (int i = 0; i < 4; ++i)
      av[i] = *(const f16x8*)&As[wm + i * 16 + l15][q * 8];
#pragma unroll
    for (int j = 0; j < 4; ++j)
      bv[j] = *(const f16x8*)&Bs[wn + j * 16 + l15][q * 8];
#pragma unroll
    for (int i = 0; i < 4; ++i)
#pragma unroll
      for (int j = 0; j < 4; ++j)
        acc[i][j] = __builtin_amdgcn_mfma_f32_16x16x32_f16(av[i], bv[j], acc[i][j], 0, 0, 0);
  }
  float bj[4];
#pragma unroll
  for (int j = 0; j < 4; ++j) bj[j] = bias[n0 + wn + j * 16 + l15];
#pragma unroll
  for (int i = 0; i < 4; ++i)
#pragma unroll
    for (int j = 0; j < 4; ++j)
#pragma unroll
      for (int r = 0; r < 4; ++r) {
        int m = m0 + wm + i * 16 + q * 4 + r;
        int n = n0 + wn + j * 16 + l15;
        U[(size_t)m * 512 + n] = (_Float16)(acc[i][j][r] + bj[j]);
      }
}

// -------------------------------------------------------------- recurrent ---
// hbuf: u64 [parity 2][batch 64][word 256]; word j = {tag32, h f16 rows 2j,2j+1}
__global__ __launch_bounds__(256, 1)
void rnn_recur(const float* __restrict__ W, const _Float16* __restrict__ U,
               unsigned long long* hbuf, float* __restrict__ out) {
  const int blk = blockIdx.x;
  const int batch = blk & 63;  // circle {b, b+64, b+128, b+192}: same XCD (%8)
  const int g = blk >> 6;      // row-slice 0..3 (rows 128g..128g+127)
  const int tid = threadIdx.x;
  const int ks = tid & 7;      // k-chunk 0..7 (64 k each) — lane-local for shfl
  const int rg = tid >> 3;     // row group 0..31 (4 rows: 128g + 4rg + i)

  // 128 KB weights, thread-order chunks (R5-proven conflict-free b128 pattern)
  __shared__ __align__(16) f16x8 wl[32][256];  // [chunk c=i*8+q][tid]
  // h staged at stride-36 u32 (R5-proven: ks-group bank = 4(ks+q)%32, distinct)
  __shared__ __align__(16) unsigned int hst[2][8 * 36];

  // One-time: rows 128g+4rg+i, cols [64ks,64ks+64) -> f16. Chunks 0..15 ALSO
  // kept in VGPRs (64 regs) — never re-read from LDS in the loop.
  f16x8 wreg[16];
#pragma unroll
  for (int i = 0; i < 4; ++i) {
    const float* wrow = W + (size_t)(128 * g + 4 * rg + i) * 1024 + ks * 64;
#pragma unroll
    for (int q = 0; q < 8; ++q) {
      float4 wa = *(const float4*)(wrow + 8 * q);
      float4 wb = *(const float4*)(wrow + 8 * q + 4);
      f16x8 pk = {(_Float16)wa.x, (_Float16)wa.y, (_Float16)wa.z, (_Float16)wa.w,
                  (_Float16)wb.x, (_Float16)wb.y, (_Float16)wb.z, (_Float16)wb.w};
      wl[i * 8 + q][tid] = pk;
      if (i * 8 + q < 16) wreg[i * 8 + q] = pk;
    }
  }

  const unsigned long long* U64 = (const unsigned long long*)U;
  unsigned long long* hb = hbuf + (size_t)batch * 256;  // parity stride NB*256

  float hv0 = 0.f, hv1 = 0.f, hv2 = 0.f, hv3 = 0.f;
  for (int t = 0; t < SEQ; ++t) {
    // U prefetch for publishers (global, vmcnt — overlaps the poll)
    unsigned long long uld = 0;
    if (ks == 0)
      uld = U64[((size_t)t * NB + batch) * 128 + 32 * g + rg];

    // prefetch weight chunks 16..23 into regs BEFORE the poll: their LDS
    // latency hides under the spin (barrier drains lgkmcnt anyway)
    f16x8 wpre[8];
#pragma unroll
    for (int j = 0; j < 8; ++j) wpre[j] = wl[16 + j][tid];
    asm volatile("" ::: "memory");  // don't sink the prefetch past the poll

    // poll word tid (rows 2tid,2tid+1) for tag t, parity t&1; stage to LDS
    {
      const unsigned long long* src = hb + (size_t)(t & 1) * (NB * 256) + tid;
      unsigned long long e;
      int spins = 0;
      for (;;) {
        e = __hip_atomic_load(src, __ATOMIC_RELAXED, __HIP_MEMORY_SCOPE_AGENT);
        if ((unsigned int)(e >> 32) == (unsigned int)t) break;
        if (++spins > 2) __builtin_amdgcn_s_sleep(1);
      }
      hst[t & 1][(tid >> 5) * 36 + (tid & 31)] = (unsigned int)e;
    }
    __syncthreads();  // ONE barrier: h_t staged (parity dbuf closes reuse race)

    // h chunk for this thread: u32 words [36ks, 36ks+32), conflict-free b128
    f16x8 h8[8];
    {
      const unsigned int* hp = &hst[t & 1][36 * ks];
#pragma unroll
      for (int q = 0; q < 8; ++q) h8[q] = *(const f16x8*)&hp[4 * q];
    }

    // 4 rows x 64 k: rows 0,1 from wreg, row 2 from wpre, row 3 streamed
    float a0 = 0.f, a1 = 0.f, a2 = 0.f, a3 = 0.f;
#pragma unroll
    for (int i = 0; i < 4; ++i) {
      float* ai = (i == 0) ? &a0 : (i == 1) ? &a1 : (i == 2) ? &a2 : &a3;
#pragma unroll
      for (int q = 0; q < 8; ++q) {
        f16x8 wv = (i < 2) ? wreg[i * 8 + q] : (i == 2) ? wpre[q] : wl[24 + q][tid];
        f16x8 hh = h8[q];
        half2v w0 = {wv[0], wv[1]}, w1 = {wv[2], wv[3]};
        half2v w2 = {wv[4], wv[5]}, w3 = {wv[6], wv[7]};
        half2v h0 = {hh[0], hh[1]}, h1 = {hh[2], hh[3]};
        half2v h2 = {hh[4], hh[5]}, h3 = {hh[6], hh[7]};
        *ai = DOT2(w0, h0, *ai); *ai = DOT2(w1, h1, *ai);
        *ai = DOT2(w2, h2, *ai); *ai = DOT2(w3, h3, *ai);
      }
    }
    // k-reduce across the 8 ks-lanes (lane-contiguous, wave-local)
#pragma unroll
    for (int m = 1; m < 8; m <<= 1) {
      a0 += __shfl_xor(a0, m);
      a1 += __shfl_xor(a1, m);
      a2 += __shfl_xor(a2, m);
      a3 += __shfl_xor(a3, m);
    }

    if (ks == 0) {
      f16x8 u8;
      *(unsigned long long*)&u8 = uld;  // 4 halves valid
      hv0 = fast_tanh(a0 + (float)u8[0]);
      hv1 = fast_tanh(a1 + (float)u8[1]);
      hv2 = fast_tanh(a2 + (float)u8[2]);
      hv3 = fast_tanh(a3 + (float)u8[3]);
      half2v p01; p01.x = (_Float16)hv0; p01.y = (_Float16)hv1;
      half2v p23; p23.x = (_Float16)hv2; p23.y = (_Float16)hv3;
      unsigned long long tg = (unsigned long long)(unsigned int)(t + 1) << 32;
      unsigned long long w01 = tg | __builtin_bit_cast(unsigned int, p01);
      unsigned long long w23 = tg | __builtin_bit_cast(unsigned int, p23);
      // publish words {64g+2rg, +1} of h_{t+1}, parity (t+1)&1 (R3 induction
      // proves the h_{t-1} overwrite is race-free)
      unsigned long long* dst =
          hb + (size_t)((t + 1) & 1) * (NB * 256) + 64 * g + 2 * rg;
      __hip_atomic_store(dst, w01, __ATOMIC_RELAXED, __HIP_MEMORY_SCOPE_AGENT);
      __hip_atomic_store(dst + 1, w23, __ATOMIC_RELAXED, __HIP_MEMORY_SCOPE_AGENT);
    }
  }
  if (ks == 0) {
    float* o = out + (size_t)batch * HID + 128 * g + 4 * rg;
    o[0] = hv0; o[1] = hv1; o[2] = hv2; o[3] = hv3;
  }
}

// ------------------------------------------------------------------- host ---
extern "C" void kernel_launch(void* const* d_in, const int* in_sizes, int n_in,
                              void* d_out, int out_size, void* d_ws, size_t ws_size,
                              hipStream_t stream) {
  const float* X    = (const float*)d_in[0];  // [1024][64][512]
  const float* W    = (const float*)d_in[1];  // [512][1024]
  const float* bias = (const float*)d_in[2];  // [512]
  float* out = (float*)d_out;                 // [64][512]

  // ws layout: U f16 (64 MiB) | hbuf u64[2][64][256] (256 KiB)
  char* ws = (char*)d_ws;
  _Float16* U = (_Float16*)ws;
  unsigned long long* hbuf =
      (unsigned long long*)(ws + (size_t)SEQ * NB * HID * 2);

  // parity-0 = h_0 = 0 with tag 0; parity-1 keeps 0xAA poison (tag 0xAAAAAAAA
  // never matches a step tag <= 1024)
  hipMemsetAsync(hbuf, 0, (size_t)NB * 256 * 8, stream);

  rnn_prepass<<<dim3(512, 4), dim3(256), 0, stream>>>(X, W, bias, U);

  const float* Wp = W;
  const _Float16* Up = U;
  unsigned long long* hb = hbuf;
  float* op = out;
  void* args[] = {(void*)&Wp, (void*)&Up, (void*)&hb, (void*)&op};
  // cooperative launch: all 256 WGs co-resident (130 KB LDS -> 1 WG/CU)
  hipError_t e = hipLaunchCooperativeKernel(
      reinterpret_cast<void*>(rnn_recur), dim3(256), dim3(256), args, 0, stream);
  if (e != hipSuccess) {
    rnn_recur<<<dim3(256), dim3(256), 0, stream>>>(Wp, Up, hb, op);
  }
}